// Round 1
// baseline (2644.210 us; speedup 1.0000x reference)
//
#include <hip/hip_runtime.h>

#define RES   32
#define NVOX  (RES * RES * RES)   // 32768
#define NB    8
#define NC    64
#define NPTS  100000

// ---------------------------------------------------------------------------
// Kernel 1: per-batch sum of coords (x,y,z) -> ws_sum[b*3+k]
// ---------------------------------------------------------------------------
__global__ void sum_kernel(const float* __restrict__ coords,
                           float* __restrict__ ws_sum) {
    const int b = blockIdx.y;
    const float* cb = coords + (size_t)b * 3 * NPTS;
    float s0 = 0.f, s1 = 0.f, s2 = 0.f;
    for (int n = blockIdx.x * blockDim.x + threadIdx.x; n < NPTS;
         n += blockDim.x * gridDim.x) {
        s0 += cb[n];
        s1 += cb[NPTS + n];
        s2 += cb[2 * NPTS + n];
    }
    // wave-64 tree reduce
    for (int off = 32; off > 0; off >>= 1) {
        s0 += __shfl_down(s0, off, 64);
        s1 += __shfl_down(s1, off, 64);
        s2 += __shfl_down(s2, off, 64);
    }
    if ((threadIdx.x & 63) == 0) {
        atomicAdd(&ws_sum[b * 3 + 0], s0);
        atomicAdd(&ws_sum[b * 3 + 1], s1);
        atomicAdd(&ws_sum[b * 3 + 2], s2);
    }
}

// ---------------------------------------------------------------------------
// Kernel 2: per-batch max squared radius of centered coords -> ws_rad[b]
// (uint atomicMax is order-preserving for non-negative floats)
// ---------------------------------------------------------------------------
__global__ void rad_kernel(const float* __restrict__ coords,
                           const float* __restrict__ ws_sum,
                           unsigned int* __restrict__ ws_rad) {
#pragma clang fp contract(off)
    const int b = blockIdx.y;
    const float* cb = coords + (size_t)b * 3 * NPTS;
    const float m0 = ws_sum[b * 3 + 0] / (float)NPTS;
    const float m1 = ws_sum[b * 3 + 1] / (float)NPTS;
    const float m2 = ws_sum[b * 3 + 2] / (float)NPTS;
    float mx = 0.f;
    for (int n = blockIdx.x * blockDim.x + threadIdx.x; n < NPTS;
         n += blockDim.x * gridDim.x) {
        float dx = cb[n] - m0;
        float dy = cb[NPTS + n] - m1;
        float dz = cb[2 * NPTS + n] - m2;
        float sq = dx * dx + dy * dy + dz * dz;
        mx = fmaxf(mx, sq);
    }
    for (int off = 32; off > 0; off >>= 1)
        mx = fmaxf(mx, __shfl_down(mx, off, 64));
    if ((threadIdx.x & 63) == 0)
        atomicMax(&ws_rad[b], __float_as_uint(mx));
}

// ---------------------------------------------------------------------------
// Kernel 3: per-point normalize, write norm_coords, scatter-add features
// ---------------------------------------------------------------------------
__global__ void scatter_kernel(const float* __restrict__ feat,
                               const float* __restrict__ coords,
                               const float* __restrict__ ws_sum,
                               const unsigned int* __restrict__ ws_rad,
                               float* __restrict__ out_sum,
                               float* __restrict__ norm_out,
                               float* __restrict__ counts) {
#pragma clang fp contract(off)
    const int n = blockIdx.x * blockDim.x + threadIdx.x;
    const int b = blockIdx.y;
    if (n >= NPTS) return;

    const float m0 = ws_sum[b * 3 + 0] / (float)NPTS;
    const float m1 = ws_sum[b * 3 + 1] / (float)NPTS;
    const float m2 = ws_sum[b * 3 + 2] / (float)NPTS;
    const float r  = sqrtf(__uint_as_float(ws_rad[b]));
    const float d  = r * 2.0f;   // EPS == 0

    const float* cb = coords + (size_t)b * 3 * NPTS;
    const float x = cb[n] - m0;
    const float y = cb[NPTS + n] - m1;
    const float z = cb[2 * NPTS + n] - m2;

    // ((c - mean)/d + 0.5) * R, clipped to [0, R-1]
    const float nx = fminf(fmaxf((x / d + 0.5f) * (float)RES, 0.0f), (float)(RES - 1));
    const float ny = fminf(fmaxf((y / d + 0.5f) * (float)RES, 0.0f), (float)(RES - 1));
    const float nz = fminf(fmaxf((z / d + 0.5f) * (float)RES, 0.0f), (float)(RES - 1));

    float* nb_ = norm_out + (size_t)b * 3 * NPTS;
    nb_[n]             = nx;
    nb_[NPTS + n]      = ny;
    nb_[2 * NPTS + n]  = nz;

    // jnp.round == round-half-to-even == rintf (default rounding mode)
    const int ix = (int)rintf(nx);
    const int iy = (int)rintf(ny);
    const int iz = (int)rintf(nz);
    const int idx = (ix * RES + iy) * RES + iz;

    atomicAdd(&counts[(size_t)b * NVOX + idx], 1.0f);

    const float* fb = feat + (size_t)b * NC * NPTS + n;
    float* ob = out_sum + (size_t)b * NC * NVOX + idx;
#pragma unroll 4
    for (int c = 0; c < NC; ++c)
        atomicAdd(ob + (size_t)c * NVOX, fb[(size_t)c * NPTS]);
}

// ---------------------------------------------------------------------------
// Kernel 4: out[b][c][v] /= max(count[b][v], 1)
// ---------------------------------------------------------------------------
__global__ void div_kernel(float* __restrict__ out_sum,
                           const float* __restrict__ counts) {
    const int t = blockIdx.x * blockDim.x + threadIdx.x;  // over NB*NVOX
    const int b = t >> 15;           // NVOX = 2^15
    const int v = t & (NVOX - 1);
    const float cnt = fmaxf(counts[t], 1.0f);
    float* ob = out_sum + (size_t)b * NC * NVOX + v;
#pragma unroll 8
    for (int c = 0; c < NC; ++c)
        ob[(size_t)c * NVOX] = ob[(size_t)c * NVOX] / cnt;
}

// ---------------------------------------------------------------------------
extern "C" void kernel_launch(void* const* d_in, const int* in_sizes, int n_in,
                              void* d_out, int out_size, void* d_ws, size_t ws_size,
                              hipStream_t stream) {
    const float* feat   = (const float*)d_in[0];  // [8,64,100000]
    const float* coords = (const float*)d_in[1];  // [8,3,100000]

    float* out      = (float*)d_out;                       // [8,64,32,32,32]
    float* norm_out = out + (size_t)NB * NC * NVOX;        // [8,3,100000]

    // workspace layout: [0..23] coord sums, [32..39] radius bits, [64..] counts
    float*        ws_sum = (float*)d_ws;
    unsigned int* ws_rad = (unsigned int*)d_ws + 32;
    float*        counts = (float*)d_ws + 64;

    hipMemsetAsync(d_ws, 0, (64 + (size_t)NB * NVOX) * sizeof(float), stream);
    hipMemsetAsync(d_out, 0, (size_t)NB * NC * NVOX * sizeof(float), stream);

    sum_kernel<<<dim3(32, NB), 256, 0, stream>>>(coords, ws_sum);
    rad_kernel<<<dim3(32, NB), 256, 0, stream>>>(coords, ws_sum, ws_rad);
    scatter_kernel<<<dim3((NPTS + 255) / 256, NB), 256, 0, stream>>>(
        feat, coords, ws_sum, ws_rad, out, norm_out, counts);
    div_kernel<<<dim3(NB * NVOX / 256), 256, 0, stream>>>(out, counts);
}

// Round 2
// 1787.552 us; speedup vs baseline: 1.4792x; 1.4792x over previous
//
#include <hip/hip_runtime.h>

#define RES   32
#define NVOX  (RES * RES * RES)   // 32768
#define NB    8
#define NC    64
#define NPTS  100000

// workspace layout in 4-byte units
#define SUM_OFF  0                              // 24 floats (pad 32)
#define RAD_OFF  32                             // 8 uints
#define CNT_OFF  64                             // NB*NVOX ints
#define OFFS_OFF (CNT_OFF  + NB * NVOX)         // NB*NVOX ints
#define CURS_OFF (OFFS_OFF + NB * NVOX)         // NB*NVOX ints
#define IDX_OFF  (CURS_OFF + NB * NVOX)         // NB*NPTS ints
#define SORT_OFF (IDX_OFF  + NB * NPTS)         // NB*NPTS uints
#define FT_OFF   (SORT_OFF + NB * NPTS)         // NB*NPTS*NC floats (optional)

// ---------------------------------------------------------------------------
// Kernel 1: per-batch sum of coords (x,y,z) -> ws_sum[b*3+k]
// ---------------------------------------------------------------------------
__global__ void sum_kernel(const float* __restrict__ coords,
                           float* __restrict__ ws_sum) {
    const int b = blockIdx.y;
    const float* cb = coords + (size_t)b * 3 * NPTS;
    float s0 = 0.f, s1 = 0.f, s2 = 0.f;
    for (int n = blockIdx.x * blockDim.x + threadIdx.x; n < NPTS;
         n += blockDim.x * gridDim.x) {
        s0 += cb[n];
        s1 += cb[NPTS + n];
        s2 += cb[2 * NPTS + n];
    }
    for (int off = 32; off > 0; off >>= 1) {
        s0 += __shfl_down(s0, off, 64);
        s1 += __shfl_down(s1, off, 64);
        s2 += __shfl_down(s2, off, 64);
    }
    if ((threadIdx.x & 63) == 0) {
        atomicAdd(&ws_sum[b * 3 + 0], s0);
        atomicAdd(&ws_sum[b * 3 + 1], s1);
        atomicAdd(&ws_sum[b * 3 + 2], s2);
    }
}

// ---------------------------------------------------------------------------
// Kernel 2: per-batch max squared radius -> ws_rad[b] (uint bits, monotone)
// ---------------------------------------------------------------------------
__global__ void rad_kernel(const float* __restrict__ coords,
                           const float* __restrict__ ws_sum,
                           unsigned int* __restrict__ ws_rad) {
#pragma clang fp contract(off)
    const int b = blockIdx.y;
    const float* cb = coords + (size_t)b * 3 * NPTS;
    const float m0 = ws_sum[b * 3 + 0] / (float)NPTS;
    const float m1 = ws_sum[b * 3 + 1] / (float)NPTS;
    const float m2 = ws_sum[b * 3 + 2] / (float)NPTS;
    float mx = 0.f;
    for (int n = blockIdx.x * blockDim.x + threadIdx.x; n < NPTS;
         n += blockDim.x * gridDim.x) {
        float dx = cb[n] - m0;
        float dy = cb[NPTS + n] - m1;
        float dz = cb[2 * NPTS + n] - m2;
        float sq = dx * dx + dy * dy + dz * dz;
        mx = fmaxf(mx, sq);
    }
    for (int off = 32; off > 0; off >>= 1)
        mx = fmaxf(mx, __shfl_down(mx, off, 64));
    if ((threadIdx.x & 63) == 0)
        atomicMax(&ws_rad[b], __float_as_uint(mx));
}

// ---------------------------------------------------------------------------
// Kernel 3: per point: norm coords (output 1), voxel idx, histogram
// ---------------------------------------------------------------------------
__global__ void index_kernel(const float* __restrict__ coords,
                             const float* __restrict__ ws_sum,
                             const unsigned int* __restrict__ ws_rad,
                             float* __restrict__ norm_out,
                             int* __restrict__ idx_arr,
                             int* __restrict__ counts) {
#pragma clang fp contract(off)
    const int n = blockIdx.x * blockDim.x + threadIdx.x;
    const int b = blockIdx.y;
    if (n >= NPTS) return;

    const float m0 = ws_sum[b * 3 + 0] / (float)NPTS;
    const float m1 = ws_sum[b * 3 + 1] / (float)NPTS;
    const float m2 = ws_sum[b * 3 + 2] / (float)NPTS;
    const float r  = sqrtf(__uint_as_float(ws_rad[b]));
    const float d  = r * 2.0f;   // EPS == 0

    const float* cb = coords + (size_t)b * 3 * NPTS;
    const float x = cb[n] - m0;
    const float y = cb[NPTS + n] - m1;
    const float z = cb[2 * NPTS + n] - m2;

    const float nx = fminf(fmaxf((x / d + 0.5f) * (float)RES, 0.0f), (float)(RES - 1));
    const float ny = fminf(fmaxf((y / d + 0.5f) * (float)RES, 0.0f), (float)(RES - 1));
    const float nz = fminf(fmaxf((z / d + 0.5f) * (float)RES, 0.0f), (float)(RES - 1));

    float* nb_ = norm_out + (size_t)b * 3 * NPTS;
    nb_[n]            = nx;
    nb_[NPTS + n]     = ny;
    nb_[2 * NPTS + n] = nz;

    const int ix = (int)rintf(nx);
    const int iy = (int)rintf(ny);
    const int iz = (int)rintf(nz);
    const int idx = (ix * RES + iy) * RES + iz;

    idx_arr[(size_t)b * NPTS + n] = idx;
    atomicAdd(&counts[b * NVOX + idx], 1);
}

// ---------------------------------------------------------------------------
// Kernel 4: per-batch exclusive scan of 32768 counts (1 block/batch, 1024 thr)
// ---------------------------------------------------------------------------
__global__ __launch_bounds__(1024) void scan_kernel(const int* __restrict__ counts,
                                                    int* __restrict__ offsets,
                                                    int* __restrict__ cursor) {
    const int b = blockIdx.x;
    const int t = threadIdx.x;            // 0..1023, each owns 32 values
    const int base = b * NVOX + t * 32;
    int sum = 0;
#pragma unroll
    for (int i = 0; i < 32; ++i) sum += counts[base + i];

    const int lane = t & 63, wid = t >> 6;  // 16 waves
    int x = sum;
    for (int off = 1; off < 64; off <<= 1) {
        int y = __shfl_up(x, off, 64);
        if (lane >= off) x += y;
    }
    __shared__ int wsum[16];
    if (lane == 63) wsum[wid] = x;
    __syncthreads();
    if (t == 0) {
        int run = 0;
        for (int w = 0; w < 16; ++w) { int tmp = wsum[w]; wsum[w] = run; run += tmp; }
    }
    __syncthreads();
    int pre = x - sum + wsum[wid];        // exclusive prefix of this chunk
#pragma unroll
    for (int i = 0; i < 32; ++i) {
        offsets[base + i] = pre;
        cursor[base + i]  = pre;
        pre += counts[base + i];
    }
}

// ---------------------------------------------------------------------------
// Kernel 5: counting-sort placement: sorted[pos] = (idx<<17)|n
// ---------------------------------------------------------------------------
__global__ void place_kernel(const int* __restrict__ idx_arr,
                             int* __restrict__ cursor,
                             unsigned int* __restrict__ sorted) {
    const int n = blockIdx.x * blockDim.x + threadIdx.x;
    const int b = blockIdx.y;
    if (n >= NPTS) return;
    const int idx = idx_arr[(size_t)b * NPTS + n];
    const int pos = atomicAdd(&cursor[b * NVOX + idx], 1);
    sorted[(size_t)b * NPTS + pos] = ((unsigned)idx << 17) | (unsigned)n;
}

// ---------------------------------------------------------------------------
// Kernel 6: feat [B][C][N] -> featT [B][N][C], LDS-tiled 64x64
// ---------------------------------------------------------------------------
__global__ void transpose_kernel(const float* __restrict__ feat,
                                 float* __restrict__ featT) {
    __shared__ float tile[64][65];
    const int b  = blockIdx.y;
    const int n0 = blockIdx.x * 64;
    const int tx = threadIdx.x & 63;
    const int ty = threadIdx.x >> 6;      // 0..3
    const float* fb = feat + (size_t)b * NC * NPTS;
    if (n0 + tx < NPTS) {
#pragma unroll
        for (int c = ty; c < 64; c += 4)
            tile[c][tx] = fb[(size_t)c * NPTS + n0 + tx];
    }
    __syncthreads();
    float* ft = featT + (size_t)b * NPTS * NC;
#pragma unroll
    for (int r = ty; r < 64; r += 4) {
        const int n = n0 + r;
        if (n < NPTS) ft[(size_t)n * NC + tx] = tile[tx][r];
    }
}

// ---------------------------------------------------------------------------
// Kernel 7: gather — block = 64 consecutive voxels, LDS tile [v][c] (pad 65),
//           lanes = channels, fused divide, coalesced output writes.
// ---------------------------------------------------------------------------
__global__ __launch_bounds__(512) void gather_kernel(
        const float* __restrict__ featT, const float* __restrict__ feat,
        const unsigned int* __restrict__ sorted,
        const int* __restrict__ offsets, const int* __restrict__ counts,
        float* __restrict__ out, int use_T) {
    __shared__ float tile[64 * 65];
    const int b    = blockIdx.y;
    const int v0   = blockIdx.x * 64;
    const int lane = threadIdx.x & 63;
    const int wid  = threadIdx.x >> 6;    // 0..7

    for (int i = threadIdx.x; i < 64 * 65; i += 512) tile[i] = 0.f;
    __syncthreads();

    const int start = offsets[b * NVOX + v0];
    const int end   = offsets[b * NVOX + v0 + 63] + counts[b * NVOX + v0 + 63];
    const unsigned int* sb = sorted + (size_t)b * NPTS;
    const float* ftb = featT + (size_t)b * NPTS * NC;
    const float* fb  = feat + (size_t)b * NC * NPTS + (size_t)lane * NPTS;

    int p = start + wid;
    if (use_T) {
        for (; p + 24 < end; p += 32) {     // 4 points/wave/iter, 8 waves
            const unsigned pk0 = sb[p], pk1 = sb[p + 8], pk2 = sb[p + 16], pk3 = sb[p + 24];
            const float f0 = ftb[(size_t)(pk0 & 0x1FFFF) * NC + lane];
            const float f1 = ftb[(size_t)(pk1 & 0x1FFFF) * NC + lane];
            const float f2 = ftb[(size_t)(pk2 & 0x1FFFF) * NC + lane];
            const float f3 = ftb[(size_t)(pk3 & 0x1FFFF) * NC + lane];
            atomicAdd(&tile[((int)(pk0 >> 17) - v0) * 65 + lane], f0);
            atomicAdd(&tile[((int)(pk1 >> 17) - v0) * 65 + lane], f1);
            atomicAdd(&tile[((int)(pk2 >> 17) - v0) * 65 + lane], f2);
            atomicAdd(&tile[((int)(pk3 >> 17) - v0) * 65 + lane], f3);
        }
        for (; p < end; p += 8) {
            const unsigned pk = sb[p];
            const float f = ftb[(size_t)(pk & 0x1FFFF) * NC + lane];
            atomicAdd(&tile[((int)(pk >> 17) - v0) * 65 + lane], f);
        }
    } else {
        for (; p < end; p += 8) {
            const unsigned pk = sb[p];
            const float f = fb[pk & 0x1FFFF];
            atomicAdd(&tile[((int)(pk >> 17) - v0) * 65 + lane], f);
        }
    }
    __syncthreads();

    const int vl = lane;
    const float cnt = fmaxf((float)counts[b * NVOX + v0 + vl], 1.f);
    float* ob = out + (size_t)b * NC * NVOX + v0 + vl;
#pragma unroll
    for (int c = wid; c < 64; c += 8)
        ob[(size_t)c * NVOX] = tile[vl * 65 + c] / cnt;
}

// ---------------------------------------------------------------------------
extern "C" void kernel_launch(void* const* d_in, const int* in_sizes, int n_in,
                              void* d_out, int out_size, void* d_ws, size_t ws_size,
                              hipStream_t stream) {
    const float* feat   = (const float*)d_in[0];  // [8,64,100000]
    const float* coords = (const float*)d_in[1];  // [8,3,100000]

    float* out      = (float*)d_out;                 // [8,64,32,32,32]
    float* norm_out = out + (size_t)NB * NC * NVOX;  // [8,3,100000]

    float*        ws_sum  = (float*)d_ws + SUM_OFF;
    unsigned int* ws_rad  = (unsigned int*)d_ws + RAD_OFF;
    int*          counts  = (int*)d_ws + CNT_OFF;
    int*          offsets = (int*)d_ws + OFFS_OFF;
    int*          cursor  = (int*)d_ws + CURS_OFF;
    int*          idx_arr = (int*)d_ws + IDX_OFF;
    unsigned int* sorted  = (unsigned int*)d_ws + SORT_OFF;
    float*        featT   = (float*)d_ws + FT_OFF;

    const size_t need_T = ((size_t)FT_OFF + (size_t)NB * NC * NPTS) * 4;
    const int use_T = (ws_size >= need_T) ? 1 : 0;

    // zero sums/rad/counts only (everything else fully written)
    hipMemsetAsync(d_ws, 0, ((size_t)CNT_OFF + (size_t)NB * NVOX) * 4, stream);

    sum_kernel<<<dim3(32, NB), 256, 0, stream>>>(coords, ws_sum);
    rad_kernel<<<dim3(32, NB), 256, 0, stream>>>(coords, ws_sum, ws_rad);
    index_kernel<<<dim3((NPTS + 255) / 256, NB), 256, 0, stream>>>(
        coords, ws_sum, ws_rad, norm_out, idx_arr, counts);
    scan_kernel<<<dim3(NB), 1024, 0, stream>>>(counts, offsets, cursor);
    place_kernel<<<dim3((NPTS + 255) / 256, NB), 256, 0, stream>>>(
        idx_arr, cursor, sorted);
    if (use_T) {
        transpose_kernel<<<dim3((NPTS + 63) / 64, NB), 256, 0, stream>>>(feat, featT);
    }
    gather_kernel<<<dim3(NVOX / 64, NB), 512, 0, stream>>>(
        featT, feat, sorted, offsets, counts, out, use_T);
}